// Round 1
// 1373.860 us; speedup vs baseline: 1.2238x; 1.2238x over previous
//
#include <hip/hip_runtime.h>

typedef unsigned short ushort_t;
typedef __attribute__((ext_vector_type(8))) short short8;
typedef __attribute__((ext_vector_type(4))) float floatx4;
typedef __attribute__((ext_vector_type(4))) unsigned short ush4;

#define MFMA16x16x32(a, b, c) __builtin_amdgcn_mfma_f32_16x16x32_bf16(a, b, c, 0, 0, 0)

__device__ __forceinline__ float bf2f(ushort_t h) {
    unsigned int u = ((unsigned int)h) << 16;
    return __builtin_bit_cast(float, u);
}
__device__ __forceinline__ ushort_t f2bf(float f) {
    unsigned int u = __builtin_bit_cast(unsigned int, f);
    u += 0x7fffu + ((u >> 16) & 1u);
    return (ushort_t)(u >> 16);
}
__device__ __forceinline__ void gload_lds16(const ushort_t* g, ushort_t* l) {
    __builtin_amdgcn_global_load_lds(
        (const __attribute__((address_space(1))) unsigned int*)g,
        (__attribute__((address_space(3))) unsigned int*)l, 16, 0, 0);
}

// ---------------------------------------------------------------------------
// fp32 -> bf16 (RNE) conversion, 8 elems/thread, grid-stride.
// ---------------------------------------------------------------------------
__global__ __launch_bounds__(256) void conv_bf16(const float* __restrict__ in,
                                                 ushort_t* __restrict__ out, int n8) {
    int i = blockIdx.x * 256 + threadIdx.x;
    const int stride = gridDim.x * 256;
    for (; i < n8; i += stride) {
        const float* p = in + (size_t)i * 8;
        floatx4 a0 = *(const floatx4*)p;
        floatx4 a1 = *(const floatx4*)(p + 4);
        short8 o;
        o[0] = (short)f2bf(a0[0]); o[1] = (short)f2bf(a0[1]);
        o[2] = (short)f2bf(a0[2]); o[3] = (short)f2bf(a0[3]);
        o[4] = (short)f2bf(a1[0]); o[5] = (short)f2bf(a1[1]);
        o[6] = (short)f2bf(a1[2]); o[7] = (short)f2bf(a1[3]);
        *(short8*)(out + (size_t)i * 8) = o;
    }
}

// ---------------------------------------------------------------------------
// LayerNorm: one block per row of 2048. INF32=1: fp32 input (original x),
// INF32=0: bf16 input (x2 residual buffer). Params bf16, output bf16.
// ---------------------------------------------------------------------------
template <int INF32>
__global__ __launch_bounds__(256) void ln_kernel(const void* __restrict__ in,
                                                 const ushort_t* __restrict__ w,
                                                 const ushort_t* __restrict__ b,
                                                 ushort_t* __restrict__ out) {
    const int row = blockIdx.x;
    const int tid = threadIdx.x;
    const size_t base = (size_t)row * 2048 + (size_t)tid * 8;
    float v[8];
    if (INF32) {
        const float* p = (const float*)in + base;
        floatx4 a0 = *(const floatx4*)p;
        floatx4 a1 = *(const floatx4*)(p + 4);
        v[0] = a0[0]; v[1] = a0[1]; v[2] = a0[2]; v[3] = a0[3];
        v[4] = a1[0]; v[5] = a1[1]; v[6] = a1[2]; v[7] = a1[3];
    } else {
        short8 hv = *(const short8*)((const ushort_t*)in + base);
        const ushort_t* hp = (const ushort_t*)&hv;
#pragma unroll
        for (int k = 0; k < 8; k++) v[k] = bf2f(hp[k]);
    }
    float s = 0.f, sq = 0.f;
#pragma unroll
    for (int k = 0; k < 8; k++) { s += v[k]; sq += v[k] * v[k]; }
#pragma unroll
    for (int m = 32; m; m >>= 1) { s += __shfl_xor(s, m); sq += __shfl_xor(sq, m); }
    __shared__ float red[8];
    const int wv = tid >> 6;
    if ((tid & 63) == 0) { red[wv] = s; red[4 + wv] = sq; }
    __syncthreads();
    s = red[0] + red[1] + red[2] + red[3];
    sq = red[4] + red[5] + red[6] + red[7];
    const float mu = s * (1.f / 2048.f);
    const float var = fmaxf(sq * (1.f / 2048.f) - mu * mu, 0.f);
    const float rs = rsqrtf(var + 1e-5f);
    short8 ov;
#pragma unroll
    for (int k = 0; k < 8; k++) {
        const int c = tid * 8 + k;
        float y = (v[k] - mu) * rs * bf2f(w[c]) + bf2f(b[c]);
        ov[k] = (short)f2bf(y);
    }
    *(short8*)(out + base) = ov;
}

// ---------------------------------------------------------------------------
// GEMM 256x256 tile, BK=64, 512 thr (8 waves, 2Mx4N; per-wave C = 128x64),
// 8-phase double-buffered schedule with counted vmcnt (T3+T4), setprio around
// MFMA clusters (T5), XOR-chunk LDS swizzle (conflict-free, T2), XCD-aware
// block swizzle + 8-row bm-group rasterization (T1).
//
// Phase plan per iteration (tiles t in buf0, t+1 in buf1), per K-tile quadrant
// order Q1=(m0-3,n0-1) Q2=(m0-3,n2-3) Q3=(m4-7,n2-3) Q4=(m4-7,n0-1):
//   B halves last read in phase 2, A halves in phase 3 of each 4-phase block.
// Staging (1 half-tile = 2 x global_load_lds / thread per phase):
//   P1: A-lo(t+1)->buf1  P2: A-hi(t+1)->buf1   (buf1 A last read prev P7)
//   P3: B-lo(t+2)->buf0  P4: B-hi(t+2)->buf0   (buf0 B last read P2)
//   P5: A-lo(t+2)->buf0  P6: A-hi(t+2)->buf0   (buf0 A last read P3)
//   P7: B-lo(t+3)->buf1  P8: B-hi(t+3)->buf1   (buf1 B last read P6)
// vmcnt(4) before the end barriers of P4/P8 guarantees the next tile fully
// landed while keeping 2 half-tiles (4 loads) in flight across the barrier.
//
// EPI 0: QKV split-store: Q (pre-scaled 1/sqrt(128)) -> out[0,32MB),
//        K -> out+16M shorts, V TRANSPOSED [b,h,d][s] -> out+32M shorts
// EPI 1: +bias +fp32 residual -> bf16 out         (attn out-proj -> x2)
// EPI 2: +bias, exact GELU -> bf16 out            (MLP up)
// EPI 3: +bias +bf16 residual -> FP32 out         (MLP down -> final output)
// ---------------------------------------------------------------------------
template <int EPI>
__global__ __launch_bounds__(512, 2) void gemm256(const ushort_t* __restrict__ A,
                                                  const ushort_t* __restrict__ W,
                                                  const ushort_t* __restrict__ bias,
                                                  const void* __restrict__ res,
                                                  void* __restrict__ out,
                                                  int M, int N, int K) {
    __shared__ ushort_t smem[65536];  // 128 KiB: As0,Bs0,As1,Bs1 each [256][64]
    ushort_t* const As0 = smem;
    ushort_t* const Bs0 = smem + 16384;
    ushort_t* const As1 = smem + 32768;
    ushort_t* const Bs1 = smem + 49152;
    const int tid = threadIdx.x;
    const int lane = tid & 63;
    const int wave = tid >> 6;
    const int la = lane & 15;
    const int qd = lane >> 4;
    const int wrow = (wave >> 2) * 128;
    const int wcol = (wave & 3) * 64;
    const int nbn = N >> 8;
    int bm, bn;
    {
        int wg = (int)blockIdx.x;
        const int cpx = (int)gridDim.x >> 3;   // all grids are %8==0 -> bijective
        wg = (wg & 7) * cpx + (wg >> 3);       // XCD-contiguous raster chunks
        const int per = 8 * nbn;               // 8-row bm groups, bn-major inside
        const int g = wg / per;
        const int rem = wg - g * per;
        bm = g * 8 + (rem & 7);
        bn = rem >> 3;
    }
    // Staging map: thread t covers row (t>>3), slot chunk (t&7); LDS slot
    // (r,c) receives global chunk c^(r&7) (source pre-swizzle; dest linear as
    // global_load_lds requires). Frag reads XOR the same way -> 0 conflicts.
    const int srow = tid >> 3;
    const int schunk = (tid & 7) ^ (srow & 7);
    const ushort_t* gA = A + (size_t)(bm * 256 + srow) * K + schunk * 8;
    const ushort_t* gB = W + (size_t)(bn * 256 + srow) * K + schunk * 8;
    const int wbase = (tid & ~63) * 8;  // wave-linear LDS base (halfwords)

    floatx4 acc[8][4];
    const floatx4 z4 = {0.f, 0.f, 0.f, 0.f};
#pragma unroll
    for (int i = 0; i < 8; i++)
#pragma unroll
        for (int j = 0; j < 4; j++) acc[i][j] = z4;
    short8 a[4][2], b[4][2];

#define GBAR()                                    \
    do {                                          \
        asm volatile("" ::: "memory");            \
        __builtin_amdgcn_s_barrier();             \
        asm volatile("" ::: "memory");            \
    } while (0)
#define GLGKM0() asm volatile("s_waitcnt lgkmcnt(0)" ::: "memory")
#define GVM4() asm volatile("s_waitcnt vmcnt(4)" ::: "memory")
#define STG(gp, lb, h, koff)                                                               \
    do {                                                                                   \
        gload_lds16((gp) + (size_t)((h) * 128) * K + (koff), (lb) + ((h) * 128) * 64 + wbase); \
        gload_lds16((gp) + (size_t)((h) * 128 + 64) * K + (koff),                          \
                    (lb) + ((h) * 128 + 64) * 64 + wbase);                                 \
    } while (0)
#define LDA4(base, mh)                                                                     \
    do {                                                                                   \
        _Pragma("unroll") for (int mi = 0; mi < 4; mi++) {                                 \
            const int row_ = wrow + (mh) * 64 + mi * 16 + la;                              \
            a[mi][0] = *(const short8*)&(base)[row_ * 64 + ((qd ^ (la & 7)) * 8)];         \
            a[mi][1] = *(const short8*)&(base)[row_ * 64 + (((4 | qd) ^ (la & 7)) * 8)];   \
        }                                                                                  \
    } while (0)
#define LDB2(base, nl)                                                                     \
    do {                                                                                   \
        _Pragma("unroll") for (int nj = 0; nj < 2; nj++) {                                 \
            const int row_ = wcol + ((nl) + nj) * 16 + la;                                 \
            b[(nl) + nj][0] = *(const short8*)&(base)[row_ * 64 + ((qd ^ (la & 7)) * 8)];  \
            b[(nl) + nj][1] =                                                              \
                *(const short8*)&(base)[row_ * 64 + (((4 | qd) ^ (la & 7)) * 8)];          \
        }                                                                                  \
    } while (0)
#define MMQ(mb, nl)                                                                        \
    do {                                                                                   \
        _Pragma("unroll") for (int ks = 0; ks < 2; ks++)                                   \
            _Pragma("unroll") for (int mi = 0; mi < 4; mi++)                               \
                _Pragma("unroll") for (int nj = 0; nj < 2; nj++) acc[(mb) + mi][(nl) + nj] = \
                    MFMA16x16x32(a[mi][ks], b[(nl) + nj][ks], acc[(mb) + mi][(nl) + nj]);  \
    } while (0)

    const int NT = K >> 6;  // K-tiles of 64 (NT even for all our shapes)
    // Prologue: tile0 (B,B,A,A) + tile1 B halves; vmcnt(4) -> tile0 landed.
    STG(gB, Bs0, 0, 0); STG(gB, Bs0, 1, 0);
    STG(gA, As0, 0, 0); STG(gA, As0, 1, 0);
    STG(gB, Bs1, 0, 64); STG(gB, Bs1, 1, 64);
    GVM4(); GBAR();

    for (int t = 0; t < NT; t += 2) {
        const size_t kA1 = (size_t)(t + 1) * 64;  // t+1 <= NT-1 always
        const size_t kT2 = (size_t)((t + 2 < NT) ? t + 2 : NT - 1) * 64;
        const size_t kB3 = (size_t)((t + 3 < NT) ? t + 3 : NT - 1) * 64;
        // P1: Q1 of tile t
        LDA4(As0, 0); LDB2(Bs0, 0); STG(gA, As1, 0, kA1);
        GBAR(); GLGKM0();
        __builtin_amdgcn_s_setprio(1); MMQ(0, 0); __builtin_amdgcn_s_setprio(0);
        GBAR();
        // P2
        LDB2(Bs0, 2); STG(gA, As1, 1, kA1);
        GBAR(); GLGKM0();
        __builtin_amdgcn_s_setprio(1); MMQ(0, 2); __builtin_amdgcn_s_setprio(0);
        GBAR();
        // P3
        LDA4(As0, 1); STG(gB, Bs0, 0, kT2);
        GBAR(); GLGKM0();
        __builtin_amdgcn_s_setprio(1); MMQ(4, 2); __builtin_amdgcn_s_setprio(0);
        GBAR();
        // P4 (no new ds-reads; vmcnt(4) -> tile t+1 fully resident past barrier)
        STG(gB, Bs0, 1, kT2);
        GBAR();
        __builtin_amdgcn_s_setprio(1); MMQ(4, 0); __builtin_amdgcn_s_setprio(0);
        GVM4(); GBAR();
        // P5: Q1 of tile t+1
        LDA4(As1, 0); LDB2(Bs1, 0); STG(gA, As0, 0, kT2);
        GBAR(); GLGKM0();
        __builtin_amdgcn_s_setprio(1); MMQ(0, 0); __builtin_amdgcn_s_setprio(0);
        GBAR();
        // P6
        LDB2(Bs1, 2); STG(gA, As0, 1, kT2);
        GBAR(); GLGKM0();
        __builtin_amdgcn_s_setprio(1); MMQ(0, 2); __builtin_amdgcn_s_setprio(0);
        GBAR();
        // P7
        LDA4(As1, 1); STG(gB, Bs1, 0, kB3);
        GBAR(); GLGKM0();
        __builtin_amdgcn_s_setprio(1); MMQ(4, 2); __builtin_amdgcn_s_setprio(0);
        GBAR();
        // P8 (vmcnt(4) -> tile t+2 fully resident past barrier)
        STG(gB, Bs1, 1, kB3);
        GBAR();
        __builtin_amdgcn_s_setprio(1); MMQ(4, 0); __builtin_amdgcn_s_setprio(0);
        GVM4(); GBAR();
    }
#undef GBAR
#undef GLGKM0
#undef GVM4
#undef STG
#undef LDA4
#undef LDB2
#undef MMQ

    if (EPI == 0) {
        // QKV split epilogue (N=6144). bn<8: Q, bn<16: K, else V transposed.
        ushort_t* q_out = (ushort_t*)out;
        if (bn < 16) {
            const float qs = (bn < 8) ? 0.08838834764831845f : 1.0f;
            ushort_t* dst = (bn < 8) ? q_out : (q_out + 16777216);
#pragma unroll
            for (int i = 0; i < 8; i++)
#pragma unroll
                for (int j = 0; j < 4; j++)
#pragma unroll
                    for (int r = 0; r < 4; r++) {
                        const int m = bm * 256 + wrow + i * 16 + qd * 4 + r;
                        const int n = bn * 256 + wcol + j * 16 + la;
                        dst[(size_t)m * 2048 + (n & 2047)] =
                            f2bf((acc[i][j][r] + bf2f(bias[n])) * qs);
                    }
        } else {
            ushort_t* v_out = q_out + 33554432;
#pragma unroll
            for (int i = 0; i < 8; i++)
#pragma unroll
                for (int j = 0; j < 4; j++) {
                    const int n = bn * 256 + wcol + j * 16 + la;  // 4096..6143
                    const int d = n - 4096;
                    const int m0 = bm * 256 + wrow + i * 16 + qd * 4;
                    const int bb = m0 >> 11, s = m0 & 2047;
                    const float bv = bf2f(bias[n]);
                    ush4 pk;
#pragma unroll
                    for (int r = 0; r < 4; r++) pk[r] = f2bf(acc[i][j][r] + bv);
                    *(ush4*)&v_out[((size_t)(bb * 2048 + d)) * 2048 + s] = pk;
                }
        }
    } else {
#pragma unroll
        for (int i = 0; i < 8; i++)
#pragma unroll
            for (int j = 0; j < 4; j++)
#pragma unroll
                for (int r = 0; r < 4; r++) {
                    const int m = bm * 256 + wrow + i * 16 + qd * 4 + r;
                    const int n = bn * 256 + wcol + j * 16 + la;
                    const size_t idx = (size_t)m * N + n;
                    float v = acc[i][j][r] + bf2f(bias[n]);
                    if (EPI == 1) {
                        v += ((const float*)res)[idx];
                        ((ushort_t*)out)[idx] = f2bf(v);
                    } else if (EPI == 2) {
                        v = 0.5f * v * (1.f + erff(v * 0.70710678118654752f));
                        ((ushort_t*)out)[idx] = f2bf(v);
                    } else {
                        v += bf2f(((const ushort_t*)res)[idx]);
                        ((float*)out)[idx] = v;
                    }
                }
    }
}

// ---------------------------------------------------------------------------
// Flash attention, ALiBi + causal. One WG (256 thr) per (b, h, 64-row q-tile).
//   - Q pre-scaled; Q frags loaded global->registers (no LDS pass).
//   - K staged [64][128] and V^T staged [128][64] via global_load_lds w=16
//     with XOR-chunk source swizzle (frag reads 2-way conflict = free).
//   - V^T comes from the pre-transposed v buffer (no in-kernel transpose).
//   - ALiBi row term dropped (softmax-invariant); causal mask diag tile only.
//   - LDS 40960 B -> 4 WG/CU.
// ---------------------------------------------------------------------------
__global__ __launch_bounds__(256, 4) void attn_kernel(const ushort_t* __restrict__ qb,
                                                      const ushort_t* __restrict__ kb,
                                                      const ushort_t* __restrict__ vtb,
                                                      const float* __restrict__ slopes,
                                                      ushort_t* __restrict__ out) {
    __shared__ ushort_t Ks[8192];   // [64 rows][16 chunks of 8]
    __shared__ ushort_t Vt[8192];   // [128 d-rows][8 chunks of 8]
    __shared__ ushort_t Ps[4096];   // 4 waves x [16][64] XOR-swizzled
    const int tid = threadIdx.x;
    const int lane = tid & 63;
    const int wave = tid >> 6;
    const int la = lane & 15;
    const int qd = lane >> 4;
    const int qt = blockIdx.x;
    const int h = blockIdx.y;
    const int b = blockIdx.z;
    const float slope = slopes[h];

    // Q fragments straight from global (one-time).
    const size_t qrow = (size_t)(b * 2048 + qt * 64 + wave * 16 + la);
    short8 qa[4];
#pragma unroll
    for (int ks = 0; ks < 4; ks++)
        qa[ks] = *(const short8*)&qb[qrow * 2048 + h * 128 + (ks * 4 + qd) * 8];

    const ushort_t* kbase = kb + ((size_t)b * 2048) * 2048 + h * 128;
    const ushort_t* vbase = vtb + ((size_t)(b * 2048 + h * 128)) * 2048;

    floatx4 accO[8];
    const floatx4 z4 = {0.f, 0.f, 0.f, 0.f};
#pragma unroll
    for (int dt = 0; dt < 8; dt++) accO[dt] = z4;
    float mst[4] = {-1e30f, -1e30f, -1e30f, -1e30f};
    float lst[4] = {0.f, 0.f, 0.f, 0.f};

    for (int kt = 0; kt <= qt; kt++) {
        __syncthreads();  // all waves done reading Ks/Vt of prev tile
        // K tile: slot f=(r,cs) holds global chunk cs^(r&15).
#pragma unroll
        for (int p = 0; p < 4; p++) {
            const int f = p * 256 + tid;
            const int r = f >> 4;
            const int cs = f & 15;
            gload_lds16(kbase + (size_t)(kt * 64 + r) * 2048 + (cs ^ (r & 15)) * 8,
                        Ks + (size_t)(p * 256 + (tid & ~63)) * 8);
        }
        // V^T tile: slot f=(d,c) holds global s-chunk c^(d&7).
#pragma unroll
        for (int p = 0; p < 4; p++) {
            const int f = p * 256 + tid;
            const int d = f >> 3;
            const int c = f & 7;
            gload_lds16(vbase + (size_t)d * 2048 + kt * 64 + (c ^ (d & 7)) * 8,
                        Vt + (size_t)(p * 256 + (tid & ~63)) * 8);
        }
        __syncthreads();

        // S = (Q/sqrt(d)) K^T  (per wave: 16 rows x 64 cols)
        floatx4 sc[4];
#pragma unroll
        for (int nt = 0; nt < 4; nt++) sc[nt] = z4;
#pragma unroll
        for (int nt = 0; nt < 4; nt++) {
#pragma unroll
            for (int ks = 0; ks < 4; ks++) {
                short8 kf = *(const short8*)&Ks[(nt * 16 + la) * 128 + ((ks * 4 + qd) ^ la) * 8];
                sc[nt] = MFMA16x16x32(qa[ks], kf, sc[nt]);
            }
        }

        // Online softmax; exp in place; P -> per-wave XOR-swizzled LDS.
        const int knb = kt * 64;
        const bool diag = (kt == qt);
        ushort_t* Pw = Ps + wave * 1024;
#pragma unroll
        for (int r = 0; r < 4; r++) {
            float rmax = -1e30f;
#pragma unroll
            for (int nt = 0; nt < 4; nt++) {
                float sval = sc[nt][r] + slope * (float)(knb + nt * 16 + la);
                if (diag && (nt * 16 + la > wave * 16 + qd * 4 + r)) sval = -1e30f;
                sc[nt][r] = sval;
                rmax = fmaxf(rmax, sval);
            }
            rmax = fmaxf(rmax, __shfl_xor(rmax, 1));
            rmax = fmaxf(rmax, __shfl_xor(rmax, 2));
            rmax = fmaxf(rmax, __shfl_xor(rmax, 4));
            rmax = fmaxf(rmax, __shfl_xor(rmax, 8));
            const float mnew = fmaxf(mst[r], rmax);
            const int row = qd * 4 + r;
            float rsum = 0.f;
#pragma unroll
            for (int nt = 0; nt < 4; nt++) {
                const float pv = __expf(sc[nt][r] - mnew);
                rsum += pv;
                const int col = nt * 16 + la;
                Pw[row * 64 + ((col >> 3) ^ (row & 7)) * 8 + (col & 7)] = f2bf(pv);
            }
            rsum += __shfl_xor(rsum, 1);
            rsum += __shfl_xor(rsum, 2);
            rsum += __shfl_xor(rsum, 4);
            rsum += __shfl_xor(rsum, 8);
            const float alpha = __expf(mst[r] - mnew);
            mst[r] = mnew;
            lst[r] = lst[r] * alpha + rsum;
#pragma unroll
            for (int dt = 0; dt < 8; dt++) accO[dt][r] *= alpha;
        }

        // O += P V
#pragma unroll
        for (int k2 = 0; k2 < 2; k2++) {
            short8 pa = *(const short8*)&Pw[la * 64 + ((k2 * 4 + qd) ^ (la & 7)) * 8];
#pragma unroll
            for (int dt = 0; dt < 8; dt++) {
                const int d = dt * 16 + la;
                short8 vf = *(const short8*)&Vt[d * 64 + ((k2 * 4 + qd) ^ (d & 7)) * 8];
                accO[dt] = MFMA16x16x32(pa, vf, accO[dt]);
            }
        }
    }

    // Normalize and store [B*S, 2048] bf16
    const size_t orow0 = (size_t)b * 2048 + qt * 64 + wave * 16 + qd * 4;
#pragma unroll
    for (int r = 0; r < 4; r++) {
        const float inv = 1.f / lst[r];
#pragma unroll
        for (int dt = 0; dt < 8; dt++)
            out[(orow0 + r) * 2048 + h * 128 + dt * 16 + la] = f2bf(accO[dt][r] * inv);
    }
}

// ---------------------------------------------------------------------------
extern "C" void kernel_launch(void* const* d_in, const int* in_sizes, int n_in,
                              void* d_out, int out_size, void* d_ws, size_t ws_size,
                              hipStream_t stream) {
    (void)in_sizes; (void)n_in; (void)out_size; (void)ws_size;
    const float* x      = (const float*)d_in[0];
    const float* ln1w   = (const float*)d_in[1];
    const float* ln1b   = (const float*)d_in[2];
    const float* Wqkv   = (const float*)d_in[3];
    const float* bqkv   = (const float*)d_in[4];
    const float* Wo     = (const float*)d_in[5];
    const float* bo     = (const float*)d_in[6];
    const float* ln2w   = (const float*)d_in[7];
    const float* ln2b   = (const float*)d_in[8];
    const float* W1     = (const float*)d_in[9];
    const float* b1     = (const float*)d_in[10];
    const float* W2     = (const float*)d_in[11];
    const float* b2     = (const float*)d_in[12];
    const float* slopes = (const float*)d_in[13];
    float* outp = (float*)d_out;

    char* ws = (char*)d_ws;
    const size_t MB = 1ull << 20;
    // Workspace (~229 MB):
    //   [0,36MB)     wbuf  bf16 rotating big-weight region
    //   [36,37MB)    small bf16 vectors
    //   [37,69MB)    h_buf bf16 [8192,2048]
    //   [69,197MB)   q@69 k@101 vt@133 attn@165 (attn phase)
    //                act [8192,8192] @69 (MLP phase, aliases all four)
    //   [197,229MB)  x2    bf16 [8192,2048]
    ushort_t* wbuf  = (ushort_t*)(ws);
    ushort_t* sv    = (ushort_t*)(ws + 36 * MB);
    ushort_t* ln1w_c = sv;            // 2048
    ushort_t* ln1b_c = sv + 2048;     // 2048
    ushort_t* bqkv_c = sv + 4096;     // 6144
    ushort_t* bo_c   = sv + 10240;    // 2048
    ushort_t* ln2w_c = sv + 12288;    // 2048
    ushort_t* ln2b_c = sv + 14336;    // 2048
    ushort_t* b1_c   = sv + 16384;    // 8192
    ushort_t* b2_c   = sv + 24576;    // 2048
    ushort_t* h_buf    = (ushort_t*)(ws + 37 * MB);
    ushort_t* q_buf    = (ushort_t*)(ws + 69 * MB);
    ushort_t* k_buf    = (ushort_t*)(ws + 101 * MB);
    ushort_t* vt_buf   = (ushort_t*)(ws + 133 * MB);
    ushort_t* attn_buf = (ushort_t*)(ws + 165 * MB);
    ushort_t* act_buf  = q_buf;
    ushort_t* x2_buf   = (ushort_t*)(ws + 197 * MB);

    const int M = 8192;  // B*S

    // ---- LN1(x) -> h ----
    conv_bf16<<<8, 256, 0, stream>>>(ln1w, ln1w_c, 2048 / 8);
    conv_bf16<<<8, 256, 0, stream>>>(ln1b, ln1b_c, 2048 / 8);
    ln_kernel<1><<<M, 256, 0, stream>>>(x, ln1w_c, ln1b_c, h_buf);
    // ---- QKV GEMM (split q/k/vt store; Q pre-scaled) ----
    conv_bf16<<<2048, 256, 0, stream>>>(Wqkv, wbuf, (6144 * 2048) / 8);
    conv_bf16<<<8, 256, 0, stream>>>(bqkv, bqkv_c, 6144 / 8);
    gemm256<0><<<(M / 256) * (6144 / 256), 512, 0, stream>>>(
        h_buf, wbuf, bqkv_c, nullptr, q_buf, M, 6144, 2048);
    // ---- Attention ----
    attn_kernel<<<dim3(32, 16, 4), 256, 0, stream>>>(q_buf, k_buf, vt_buf, slopes, attn_buf);
    // ---- Out-proj + residual -> x2 (bf16) ----
    conv_bf16<<<1024, 256, 0, stream>>>(Wo, wbuf, (2048 * 2048) / 8);
    conv_bf16<<<8, 256, 0, stream>>>(bo, bo_c, 2048 / 8);
    gemm256<1><<<(M / 256) * (2048 / 256), 512, 0, stream>>>(
        attn_buf, wbuf, bo_c, x, x2_buf, M, 2048, 2048);
    // ---- LN2(x2) -> h ----
    conv_bf16<<<8, 256, 0, stream>>>(ln2w, ln2w_c, 2048 / 8);
    conv_bf16<<<8, 256, 0, stream>>>(ln2b, ln2b_c, 2048 / 8);
    ln_kernel<0><<<M, 256, 0, stream>>>(x2_buf, ln2w_c, ln2b_c, h_buf);
    // ---- MLP up + GELU ----
    conv_bf16<<<2048, 256, 0, stream>>>(W1, wbuf, (8192 * 2048) / 8);
    conv_bf16<<<8, 256, 0, stream>>>(b1, b1_c, 8192 / 8);
    gemm256<2><<<(M / 256) * (8192 / 256), 512, 0, stream>>>(
        h_buf, wbuf, b1_c, nullptr, act_buf, M, 8192, 2048);
    // ---- MLP down + residual -> out (fp32) ----
    conv_bf16<<<2048, 256, 0, stream>>>(W2, wbuf, (2048 * 8192) / 8);
    conv_bf16<<<8, 256, 0, stream>>>(b2, b2_c, 2048 / 8);
    gemm256<3><<<(M / 256) * (2048 / 256), 512, 0, stream>>>(
        act_buf, wbuf, b2_c, x2_buf, outp, M, 2048, 8192);
}

// Round 2
// 1251.833 us; speedup vs baseline: 1.3431x; 1.0975x over previous
//
#include <hip/hip_runtime.h>

typedef unsigned short ushort_t;
typedef __attribute__((ext_vector_type(8))) short short8;
typedef __attribute__((ext_vector_type(4))) float floatx4;
typedef __attribute__((ext_vector_type(4))) unsigned short ush4;

#define MFMA16x16x32(a, b, c) __builtin_amdgcn_mfma_f32_16x16x32_bf16(a, b, c, 0, 0, 0)

__device__ __forceinline__ float bf2f(ushort_t h) {
    unsigned int u = ((unsigned int)h) << 16;
    return __builtin_bit_cast(float, u);
}
__device__ __forceinline__ ushort_t f2bf(float f) {
    unsigned int u = __builtin_bit_cast(unsigned int, f);
    u += 0x7fffu + ((u >> 16) & 1u);
    return (ushort_t)(u >> 16);
}
__device__ __forceinline__ void gload_lds16(const ushort_t* g, ushort_t* l) {
    __builtin_amdgcn_global_load_lds(
        (const __attribute__((address_space(1))) unsigned int*)g,
        (__attribute__((address_space(3))) unsigned int*)l, 16, 0, 0);
}

// ---------------------------------------------------------------------------
// fp32 -> bf16 (RNE) conversion, 8 elems/thread, grid-stride.
// ---------------------------------------------------------------------------
__global__ __launch_bounds__(256) void conv_bf16(const float* __restrict__ in,
                                                 ushort_t* __restrict__ out, int n8) {
    int i = blockIdx.x * 256 + threadIdx.x;
    const int stride = gridDim.x * 256;
    for (; i < n8; i += stride) {
        const float* p = in + (size_t)i * 8;
        floatx4 a0 = *(const floatx4*)p;
        floatx4 a1 = *(const floatx4*)(p + 4);
        short8 o;
        o[0] = (short)f2bf(a0[0]); o[1] = (short)f2bf(a0[1]);
        o[2] = (short)f2bf(a0[2]); o[3] = (short)f2bf(a0[3]);
        o[4] = (short)f2bf(a1[0]); o[5] = (short)f2bf(a1[1]);
        o[6] = (short)f2bf(a1[2]); o[7] = (short)f2bf(a1[3]);
        *(short8*)(out + (size_t)i * 8) = o;
    }
}

// ---------------------------------------------------------------------------
// LayerNorm: one block per row of 2048. INF32=1: fp32 input (original x),
// INF32=0: bf16 input (x2 residual buffer). Params bf16, output bf16.
// ---------------------------------------------------------------------------
template <int INF32>
__global__ __launch_bounds__(256) void ln_kernel(const void* __restrict__ in,
                                                 const ushort_t* __restrict__ w,
                                                 const ushort_t* __restrict__ b,
                                                 ushort_t* __restrict__ out) {
    const int row = blockIdx.x;
    const int tid = threadIdx.x;
    const size_t base = (size_t)row * 2048 + (size_t)tid * 8;
    float v[8];
    if (INF32) {
        const float* p = (const float*)in + base;
        floatx4 a0 = *(const floatx4*)p;
        floatx4 a1 = *(const floatx4*)(p + 4);
        v[0] = a0[0]; v[1] = a0[1]; v[2] = a0[2]; v[3] = a0[3];
        v[4] = a1[0]; v[5] = a1[1]; v[6] = a1[2]; v[7] = a1[3];
    } else {
        short8 hv = *(const short8*)((const ushort_t*)in + base);
        const ushort_t* hp = (const ushort_t*)&hv;
#pragma unroll
        for (int k = 0; k < 8; k++) v[k] = bf2f(hp[k]);
    }
    float s = 0.f, sq = 0.f;
#pragma unroll
    for (int k = 0; k < 8; k++) { s += v[k]; sq += v[k] * v[k]; }
#pragma unroll
    for (int m = 32; m; m >>= 1) { s += __shfl_xor(s, m); sq += __shfl_xor(sq, m); }
    __shared__ float red[8];
    const int wv = tid >> 6;
    if ((tid & 63) == 0) { red[wv] = s; red[4 + wv] = sq; }
    __syncthreads();
    s = red[0] + red[1] + red[2] + red[3];
    sq = red[4] + red[5] + red[6] + red[7];
    const float mu = s * (1.f / 2048.f);
    const float var = fmaxf(sq * (1.f / 2048.f) - mu * mu, 0.f);
    const float rs = rsqrtf(var + 1e-5f);
    short8 ov;
#pragma unroll
    for (int k = 0; k < 8; k++) {
        const int c = tid * 8 + k;
        float y = (v[k] - mu) * rs * bf2f(w[c]) + bf2f(b[c]);
        ov[k] = (short)f2bf(y);
    }
    *(short8*)(out + base) = ov;
}

// ---------------------------------------------------------------------------
// GEMM 256x256 tile, BK=64, 512 thr (8 waves, 2Mx4N; per-wave C = 128x64),
// 8-phase double-buffered schedule with counted vmcnt (T3+T4), setprio around
// MFMA clusters (T5), XOR-chunk LDS swizzle (conflict-free, T2), XCD-aware
// block swizzle + 8-row bm-group rasterization (T1).
//
// EPI 0: QKV split-store: Q (pre-scaled log2e/sqrt(128)) -> out[0,32MB),
//        K -> out+16M shorts, V TRANSPOSED [b,h,d][s] -> out+32M shorts
// EPI 1: +bias +fp32 residual -> bf16 out         (attn out-proj -> x2)
// EPI 2: +bias, exact GELU -> bf16 out            (MLP up)
// EPI 3: +bias +bf16 residual -> FP32 out         (MLP down -> final output)
// ---------------------------------------------------------------------------
template <int EPI>
__global__ __launch_bounds__(512, 2) void gemm256(const ushort_t* __restrict__ A,
                                                  const ushort_t* __restrict__ W,
                                                  const ushort_t* __restrict__ bias,
                                                  const void* __restrict__ res,
                                                  void* __restrict__ out,
                                                  int M, int N, int K) {
    __shared__ ushort_t smem[65536];  // 128 KiB: As0,Bs0,As1,Bs1 each [256][64]
    ushort_t* const As0 = smem;
    ushort_t* const Bs0 = smem + 16384;
    ushort_t* const As1 = smem + 32768;
    ushort_t* const Bs1 = smem + 49152;
    const int tid = threadIdx.x;
    const int lane = tid & 63;
    const int wave = tid >> 6;
    const int la = lane & 15;
    const int qd = lane >> 4;
    const int wrow = (wave >> 2) * 128;
    const int wcol = (wave & 3) * 64;
    const int nbn = N >> 8;
    int bm, bn;
    {
        int wg = (int)blockIdx.x;
        const int cpx = (int)gridDim.x >> 3;   // all grids are %8==0 -> bijective
        wg = (wg & 7) * cpx + (wg >> 3);       // XCD-contiguous raster chunks
        const int per = 8 * nbn;               // 8-row bm groups, bn-major inside
        const int g = wg / per;
        const int rem = wg - g * per;
        bm = g * 8 + (rem & 7);
        bn = rem >> 3;
    }
    // Staging map: thread t covers row (t>>3), slot chunk (t&7); LDS slot
    // (r,c) receives global chunk c^(r&7) (source pre-swizzle; dest linear as
    // global_load_lds requires). Frag reads XOR the same way -> 0 conflicts.
    const int srow = tid >> 3;
    const int schunk = (tid & 7) ^ (srow & 7);
    const ushort_t* gA = A + (size_t)(bm * 256 + srow) * K + schunk * 8;
    const ushort_t* gB = W + (size_t)(bn * 256 + srow) * K + schunk * 8;
    const int wbase = (tid & ~63) * 8;  // wave-linear LDS base (halfwords)

    floatx4 acc[8][4];
    const floatx4 z4 = {0.f, 0.f, 0.f, 0.f};
#pragma unroll
    for (int i = 0; i < 8; i++)
#pragma unroll
        for (int j = 0; j < 4; j++) acc[i][j] = z4;
    short8 a[4][2], b[4][2];

#define GBAR()                                    \
    do {                                          \
        asm volatile("" ::: "memory");            \
        __builtin_amdgcn_s_barrier();             \
        asm volatile("" ::: "memory");            \
    } while (0)
#define GLGKM0() asm volatile("s_waitcnt lgkmcnt(0)" ::: "memory")
#define GVM4() asm volatile("s_waitcnt vmcnt(4)" ::: "memory")
#define STG(gp, lb, h, koff)                                                               \
    do {                                                                                   \
        gload_lds16((gp) + (size_t)((h) * 128) * K + (koff), (lb) + ((h) * 128) * 64 + wbase); \
        gload_lds16((gp) + (size_t)((h) * 128 + 64) * K + (koff),                          \
                    (lb) + ((h) * 128 + 64) * 64 + wbase);                                 \
    } while (0)
#define LDA4(base, mh)                                                                     \
    do {                                                                                   \
        _Pragma("unroll") for (int mi = 0; mi < 4; mi++) {                                 \
            const int row_ = wrow + (mh) * 64 + mi * 16 + la;                              \
            a[mi][0] = *(const short8*)&(base)[row_ * 64 + ((qd ^ (la & 7)) * 8)];         \
            a[mi][1] = *(const short8*)&(base)[row_ * 64 + (((4 | qd) ^ (la & 7)) * 8)];   \
        }                                                                                  \
    } while (0)
#define LDB2(base, nl)                                                                     \
    do {                                                                                   \
        _Pragma("unroll") for (int nj = 0; nj < 2; nj++) {                                 \
            const int row_ = wcol + ((nl) + nj) * 16 + la;                                 \
            b[(nl) + nj][0] = *(const short8*)&(base)[row_ * 64 + ((qd ^ (la & 7)) * 8)];  \
            b[(nl) + nj][1] =                                                              \
                *(const short8*)&(base)[row_ * 64 + (((4 | qd) ^ (la & 7)) * 8)];          \
        }                                                                                  \
    } while (0)
#define MMQ(mb, nl)                                                                        \
    do {                                                                                   \
        _Pragma("unroll") for (int ks = 0; ks < 2; ks++)                                   \
            _Pragma("unroll") for (int mi = 0; mi < 4; mi++)                               \
                _Pragma("unroll") for (int nj = 0; nj < 2; nj++) acc[(mb) + mi][(nl) + nj] = \
                    MFMA16x16x32(a[mi][ks], b[(nl) + nj][ks], acc[(mb) + mi][(nl) + nj]);  \
    } while (0)

    const int NT = K >> 6;  // K-tiles of 64 (NT even for all our shapes)
    // Prologue: tile0 (B,B,A,A) + tile1 B halves; vmcnt(4) -> tile0 landed.
    STG(gB, Bs0, 0, 0); STG(gB, Bs0, 1, 0);
    STG(gA, As0, 0, 0); STG(gA, As0, 1, 0);
    STG(gB, Bs1, 0, 64); STG(gB, Bs1, 1, 64);
    GVM4(); GBAR();

    for (int t = 0; t < NT; t += 2) {
        const size_t kA1 = (size_t)(t + 1) * 64;  // t+1 <= NT-1 always
        const size_t kT2 = (size_t)((t + 2 < NT) ? t + 2 : NT - 1) * 64;
        const size_t kB3 = (size_t)((t + 3 < NT) ? t + 3 : NT - 1) * 64;
        // P1: Q1 of tile t
        LDA4(As0, 0); LDB2(Bs0, 0); STG(gA, As1, 0, kA1);
        GBAR(); GLGKM0();
        __builtin_amdgcn_s_setprio(1); MMQ(0, 0); __builtin_amdgcn_s_setprio(0);
        GBAR();
        // P2
        LDB2(Bs0, 2); STG(gA, As1, 1, kA1);
        GBAR(); GLGKM0();
        __builtin_amdgcn_s_setprio(1); MMQ(0, 2); __builtin_amdgcn_s_setprio(0);
        GBAR();
        // P3
        LDA4(As0, 1); STG(gB, Bs0, 0, kT2);
        GBAR(); GLGKM0();
        __builtin_amdgcn_s_setprio(1); MMQ(4, 2); __builtin_amdgcn_s_setprio(0);
        GBAR();
        // P4 (no new ds-reads; vmcnt(4) -> tile t+1 fully resident past barrier)
        STG(gB, Bs0, 1, kT2);
        GBAR();
        __builtin_amdgcn_s_setprio(1); MMQ(4, 0); __builtin_amdgcn_s_setprio(0);
        GVM4(); GBAR();
        // P5: Q1 of tile t+1
        LDA4(As1, 0); LDB2(Bs1, 0); STG(gA, As0, 0, kT2);
        GBAR(); GLGKM0();
        __builtin_amdgcn_s_setprio(1); MMQ(0, 0); __builtin_amdgcn_s_setprio(0);
        GBAR();
        // P6
        LDB2(Bs1, 2); STG(gA, As0, 1, kT2);
        GBAR(); GLGKM0();
        __builtin_amdgcn_s_setprio(1); MMQ(0, 2); __builtin_amdgcn_s_setprio(0);
        GBAR();
        // P7
        LDA4(As1, 1); STG(gB, Bs1, 0, kB3);
        GBAR(); GLGKM0();
        __builtin_amdgcn_s_setprio(1); MMQ(4, 2); __builtin_amdgcn_s_setprio(0);
        GBAR();
        // P8 (vmcnt(4) -> tile t+2 fully resident past barrier)
        STG(gB, Bs1, 1, kB3);
        GBAR();
        __builtin_amdgcn_s_setprio(1); MMQ(4, 0); __builtin_amdgcn_s_setprio(0);
        GVM4(); GBAR();
    }
#undef GBAR
#undef GLGKM0
#undef GVM4
#undef STG
#undef LDA4
#undef LDB2
#undef MMQ

    if (EPI == 0) {
        // QKV split epilogue (N=6144). bn<8: Q, bn<16: K, else V transposed.
        ushort_t* q_out = (ushort_t*)out;
        if (bn < 16) {
            // Q pre-scale: log2(e)/sqrt(128) (exp2-domain softmax downstream)
            const float qs = (bn < 8) ? (0.08838834764831845f * 1.4426950408889634f) : 1.0f;
            ushort_t* dst = (bn < 8) ? q_out : (q_out + 16777216);
#pragma unroll
            for (int i = 0; i < 8; i++)
#pragma unroll
                for (int j = 0; j < 4; j++)
#pragma unroll
                    for (int r = 0; r < 4; r++) {
                        const int m = bm * 256 + wrow + i * 16 + qd * 4 + r;
                        const int n = bn * 256 + wcol + j * 16 + la;
                        dst[(size_t)m * 2048 + (n & 2047)] =
                            f2bf((acc[i][j][r] + bf2f(bias[n])) * qs);
                    }
        } else {
            ushort_t* v_out = q_out + 33554432;
#pragma unroll
            for (int i = 0; i < 8; i++)
#pragma unroll
                for (int j = 0; j < 4; j++) {
                    const int n = bn * 256 + wcol + j * 16 + la;  // 4096..6143
                    const int d = n - 4096;
                    const int m0 = bm * 256 + wrow + i * 16 + qd * 4;
                    const int bb = m0 >> 11, s = m0 & 2047;
                    const float bv = bf2f(bias[n]);
                    ush4 pk;
#pragma unroll
                    for (int r = 0; r < 4; r++) pk[r] = f2bf(acc[i][j][r] + bv);
                    *(ush4*)&v_out[((size_t)(bb * 2048 + d)) * 2048 + s] = pk;
                }
        }
    } else {
#pragma unroll
        for (int i = 0; i < 8; i++)
#pragma unroll
            for (int j = 0; j < 4; j++)
#pragma unroll
                for (int r = 0; r < 4; r++) {
                    const int m = bm * 256 + wrow + i * 16 + qd * 4 + r;
                    const int n = bn * 256 + wcol + j * 16 + la;
                    const size_t idx = (size_t)m * N + n;
                    float v = acc[i][j][r] + bf2f(bias[n]);
                    if (EPI == 1) {
                        v += ((const float*)res)[idx];
                        ((ushort_t*)out)[idx] = f2bf(v);
                    } else if (EPI == 2) {
                        v = 0.5f * v * (1.f + erff(v * 0.70710678118654752f));
                        ((ushort_t*)out)[idx] = f2bf(v);
                    } else {
                        v += bf2f(((const ushort_t*)res)[idx]);
                        ((float*)out)[idx] = v;
                    }
                }
    }
}

// ---------------------------------------------------------------------------
// Flash attention, ALiBi + causal. One WG (256 thr) per (b, h, 64-row q-tile).
//   - Q pre-scaled by log2e/sqrt(d) (exp2-domain softmax; slope folded too).
//   - K [64][128] and V^T [128][64] DOUBLE-BUFFERED in LDS via gload_lds w=16
//     with XOR-chunk source swizzle; next tile's 8 DMA loads stay in flight
//     across the compute phase (counted vmcnt(8) + raw s_barrier, T3/T4).
//   - 1-D grid, XCD-grouped: each XCD owns 8 whole (b,h) pairs (K/V L2 reuse),
//     qt DESCENDING within pair (LPT schedule for the causal triangle).
//   - LDS 73728 B -> 2 WG/CU (8 waves).
// ---------------------------------------------------------------------------
__global__ __launch_bounds__(256, 2) void attn_kernel(const ushort_t* __restrict__ qb,
                                                      const ushort_t* __restrict__ kb,
                                                      const ushort_t* __restrict__ vtb,
                                                      const float* __restrict__ slopes,
                                                      ushort_t* __restrict__ out) {
    __shared__ ushort_t Ks[16384];  // 2 x [64 rows][16 chunks of 8]
    __shared__ ushort_t Vt[16384];  // 2 x [128 d-rows][8 chunks of 8]
    __shared__ ushort_t Ps[4096];   // 4 waves x [16][64] XOR-swizzled
    const int tid = threadIdx.x;
    const int lane = tid & 63;
    const int wave = tid >> 6;
    const int la = lane & 15;
    const int qd = lane >> 4;
    // XCD-grouped LPT decomposition: lid&7 = XCD (round-robin heuristic);
    // each XCD hosts pairs p = (lid&7)*8 + (lid>>8); qt descends within pair.
    const int lid = (int)blockIdx.x;  // 0..2047
    const int pair = (lid & 7) * 8 + (lid >> 8);
    const int h = pair & 15;
    const int b = pair >> 4;
    const int qt = 31 - ((lid >> 3) & 31);
    const float slope2 = slopes[h] * 1.4426950408889634f;  // log2e fold

    // Q fragments straight from global (one-time).
    const size_t qrow = (size_t)(b * 2048 + qt * 64 + wave * 16 + la);
    short8 qa[4];
#pragma unroll
    for (int ks = 0; ks < 4; ks++)
        qa[ks] = *(const short8*)&qb[qrow * 2048 + h * 128 + (ks * 4 + qd) * 8];

    const ushort_t* kbase = kb + ((size_t)b * 2048) * 2048 + h * 128;
    const ushort_t* vbase = vtb + ((size_t)(b * 2048 + h * 128)) * 2048;

    floatx4 accO[8];
    const floatx4 z4 = {0.f, 0.f, 0.f, 0.f};
#pragma unroll
    for (int dt = 0; dt < 8; dt++) accO[dt] = z4;
    float mst[4] = {-1e30f, -1e30f, -1e30f, -1e30f};
    float lst[4] = {0.f, 0.f, 0.f, 0.f};

    // Issue the 8 DMA loads (4 K + 4 V^T) of tile kt_ into buffer buf_.
    // K slot f=(r,cs) holds global chunk cs^(r&15); V^T slot f=(d,c) holds
    // global s-chunk c^(d&7).
#define AISSUE(kt_, buf_)                                                                   \
    do {                                                                                    \
        _Pragma("unroll") for (int p_ = 0; p_ < 4; p_++) {                                  \
            const int f_ = p_ * 256 + tid;                                                  \
            const int r_ = f_ >> 4;                                                         \
            const int cs_ = f_ & 15;                                                        \
            gload_lds16(kbase + (size_t)((kt_) * 64 + r_) * 2048 + (cs_ ^ (r_ & 15)) * 8,   \
                        Ks + (buf_) * 8192 + (size_t)(p_ * 256 + (tid & ~63)) * 8);         \
        }                                                                                   \
        _Pragma("unroll") for (int p_ = 0; p_ < 4; p_++) {                                  \
            const int f_ = p_ * 256 + tid;                                                  \
            const int d_ = f_ >> 3;                                                         \
            const int c_ = f_ & 7;                                                          \
            gload_lds16(vbase + (size_t)d_ * 2048 + (kt_) * 64 + (c_ ^ (d_ & 7)) * 8,       \
                        Vt + (buf_) * 8192 + (size_t)(p_ * 256 + (tid & ~63)) * 8);         \
        }                                                                                   \
    } while (0)
#define ABAR()                                    \
    do {                                          \
        asm volatile("" ::: "memory");            \
        __builtin_amdgcn_s_barrier();             \
        asm volatile("" ::: "memory");            \
    } while (0)

    AISSUE(0, 0);
    for (int kt = 0; kt <= qt; kt++) {
        const int cur = kt & 1;
        if (kt < qt) {
            AISSUE(kt + 1, cur ^ 1);  // prefetch next tile into the other buffer
            asm volatile("s_waitcnt vmcnt(8)" ::: "memory");  // my tile-kt loads done
        } else {
            asm volatile("s_waitcnt vmcnt(0)" ::: "memory");
        }
        ABAR();  // all waves' tile-kt loads landed & visible
        const ushort_t* Kc = Ks + cur * 8192;
        const ushort_t* Vc = Vt + cur * 8192;

        // S = (Q*log2e/sqrt(d)) K^T  (per wave: 16 rows x 64 cols)
        floatx4 sc[4];
#pragma unroll
        for (int nt = 0; nt < 4; nt++) sc[nt] = z4;
#pragma unroll
        for (int nt = 0; nt < 4; nt++) {
#pragma unroll
            for (int ks = 0; ks < 4; ks++) {
                short8 kf = *(const short8*)&Kc[(nt * 16 + la) * 128 + ((ks * 4 + qd) ^ la) * 8];
                sc[nt] = MFMA16x16x32(qa[ks], kf, sc[nt]);
            }
        }

        // Online softmax (log2 domain); exp2 in place; P -> per-wave LDS.
        const int knb = kt * 64;
        const bool diag = (kt == qt);
        ushort_t* Pw = Ps + wave * 1024;
        float acol[4];
#pragma unroll
        for (int nt = 0; nt < 4; nt++)
            acol[nt] = slope2 * (float)(knb + nt * 16 + la);
#pragma unroll
        for (int r = 0; r < 4; r++) {
            float rmax = -1e30f;
#pragma unroll
            for (int nt = 0; nt < 4; nt++) {
                float sval = sc[nt][r] + acol[nt];
                if (diag && (nt * 16 + la > wave * 16 + qd * 4 + r)) sval = -1e30f;
                sc[nt][r] = sval;
                rmax = fmaxf(rmax, sval);
            }
            rmax = fmaxf(rmax, __shfl_xor(rmax, 1));
            rmax = fmaxf(rmax, __shfl_xor(rmax, 2));
            rmax = fmaxf(rmax, __shfl_xor(rmax, 4));
            rmax = fmaxf(rmax, __shfl_xor(rmax, 8));
            const float mnew = fmaxf(mst[r], rmax);
            const int row = qd * 4 + r;
            float rsum = 0.f;
#pragma unroll
            for (int nt = 0; nt < 4; nt++) {
                const float pv = __builtin_amdgcn_exp2f(sc[nt][r] - mnew);
                rsum += pv;
                const int col = nt * 16 + la;
                Pw[row * 64 + ((col >> 3) ^ (row & 7)) * 8 + (col & 7)] = f2bf(pv);
            }
            rsum += __shfl_xor(rsum, 1);
            rsum += __shfl_xor(rsum, 2);
            rsum += __shfl_xor(rsum, 4);
            rsum += __shfl_xor(rsum, 8);
            const float alpha = __builtin_amdgcn_exp2f(mst[r] - mnew);
            mst[r] = mnew;
            lst[r] = lst[r] * alpha + rsum;
#pragma unroll
            for (int dt = 0; dt < 8; dt++) accO[dt][r] *= alpha;
        }

        // O += P V
#pragma unroll
        for (int k2 = 0; k2 < 2; k2++) {
            short8 pa = *(const short8*)&Pw[la * 64 + ((k2 * 4 + qd) ^ (la & 7)) * 8];
#pragma unroll
            for (int dt = 0; dt < 8; dt++) {
                const int d = dt * 16 + la;
                short8 vf = *(const short8*)&Vc[d * 64 + ((k2 * 4 + qd) ^ (d & 7)) * 8];
                accO[dt] = MFMA16x16x32(pa, vf, accO[dt]);
            }
        }
        ABAR();  // all waves done reading cur buf before next prefetch overwrites
    }
#undef AISSUE
#undef ABAR

    // Normalize and store [B*S, 2048] bf16
    const size_t orow0 = (size_t)b * 2048 + qt * 64 + wave * 16 + qd * 4;
#pragma unroll
    for (int r = 0; r < 4; r++) {
        const float inv = 1.f / lst[r];
#pragma unroll
        for (int dt = 0; dt < 8; dt++)
            out[(orow0 + r) * 2048 + h * 128 + dt * 16 + la] = f2bf(accO[dt][r] * inv);
    }
}

// ---------------------------------------------------------------------------
extern "C" void kernel_launch(void* const* d_in, const int* in_sizes, int n_in,
                              void* d_out, int out_size, void* d_ws, size_t ws_size,
                              hipStream_t stream) {
    (void)in_sizes; (void)n_in; (void)out_size; (void)ws_size;
    const float* x      = (const float*)d_in[0];
    const float* ln1w   = (const float*)d_in[1];
    const float* ln1b   = (const float*)d_in[2];
    const float* Wqkv   = (const float*)d_in[3];
    const float* bqkv   = (const float*)d_in[4];
    const float* Wo     = (const float*)d_in[5];
    const float* bo     = (const float*)d_in[6];
    const float* ln2w   = (const float*)d_in[7];
    const float* ln2b   = (const float*)d_in[8];
    const float* W1     = (const float*)d_in[9];
    const float* b1     = (const float*)d_in[10];
    const float* W2     = (const float*)d_in[11];
    const float* b2     = (const float*)d_in[12];
    const float* slopes = (const float*)d_in[13];
    float* outp = (float*)d_out;

    char* ws = (char*)d_ws;
    const size_t MB = 1ull << 20;
    // Workspace (~229 MB):
    //   [0,36MB)     wbuf  bf16 rotating big-weight region
    //   [36,37MB)    small bf16 vectors
    //   [37,69MB)    h_buf bf16 [8192,2048]
    //   [69,197MB)   q@69 k@101 vt@133 attn@165 (attn phase)
    //                act [8192,8192] @69 (MLP phase, aliases all four)
    //   [197,229MB)  x2    bf16 [8192,2048]
    ushort_t* wbuf  = (ushort_t*)(ws);
    ushort_t* sv    = (ushort_t*)(ws + 36 * MB);
    ushort_t* ln1w_c = sv;            // 2048
    ushort_t* ln1b_c = sv + 2048;     // 2048
    ushort_t* bqkv_c = sv + 4096;     // 6144
    ushort_t* bo_c   = sv + 10240;    // 2048
    ushort_t* ln2w_c = sv + 12288;    // 2048
    ushort_t* ln2b_c = sv + 14336;    // 2048
    ushort_t* b1_c   = sv + 16384;    // 8192
    ushort_t* b2_c   = sv + 24576;    // 2048
    ushort_t* h_buf    = (ushort_t*)(ws + 37 * MB);
    ushort_t* q_buf    = (ushort_t*)(ws + 69 * MB);
    ushort_t* k_buf    = (ushort_t*)(ws + 101 * MB);
    ushort_t* vt_buf   = (ushort_t*)(ws + 133 * MB);
    ushort_t* attn_buf = (ushort_t*)(ws + 165 * MB);
    ushort_t* act_buf  = q_buf;
    ushort_t* x2_buf   = (ushort_t*)(ws + 197 * MB);

    const int M = 8192;  // B*S

    // ---- LN1(x) -> h ----
    conv_bf16<<<8, 256, 0, stream>>>(ln1w, ln1w_c, 2048 / 8);
    conv_bf16<<<8, 256, 0, stream>>>(ln1b, ln1b_c, 2048 / 8);
    ln_kernel<1><<<M, 256, 0, stream>>>(x, ln1w_c, ln1b_c, h_buf);
    // ---- QKV GEMM (split q/k/vt store; Q pre-scaled) ----
    conv_bf16<<<2048, 256, 0, stream>>>(Wqkv, wbuf, (6144 * 2048) / 8);
    conv_bf16<<<8, 256, 0, stream>>>(bqkv, bqkv_c, 6144 / 8);
    gemm256<0><<<(M / 256) * (6144 / 256), 512, 0, stream>>>(
        h_buf, wbuf, bqkv_c, nullptr, q_buf, M, 6144, 2048);
    // ---- Attention (1-D grid: XCD-grouped pairs, LPT qt order) ----
    attn_kernel<<<2048, 256, 0, stream>>>(q_buf, k_buf, vt_buf, slopes, attn_buf);
    // ---- Out-proj + residual -> x2 (bf16) ----
    conv_bf16<<<1024, 256, 0, stream>>>(Wo, wbuf, (2048 * 2048) / 8);
    conv_bf16<<<8, 256, 0, stream>>>(bo, bo_c, 2048 / 8);
    gemm256<1><<<(M / 256) * (2048 / 256), 512, 0, stream>>>(
        attn_buf, wbuf, bo_c, x, x2_buf, M, 2048, 2048);
    // ---- LN2(x2) -> h ----
    conv_bf16<<<8, 256, 0, stream>>>(ln2w, ln2w_c, 2048 / 8);
    conv_bf16<<<8, 256, 0, stream>>>(ln2b, ln2b_c, 2048 / 8);
    ln_kernel<0><<<M, 256, 0, stream>>>(x2_buf, ln2w_c, ln2b_c, h_buf);
    // ---- MLP up + GELU ----
    conv_bf16<<<2048, 256, 0, stream>>>(W1, wbuf, (8192 * 2048) / 8);
    conv_bf16<<<8, 256, 0, stream>>>(b1, b1_c, 8192 / 8);
    gemm256<2><<<(M / 256) * (8192 / 256), 512, 0, stream>>>(
        h_buf, wbuf, b1_c, nullptr, act_buf, M, 8192, 2048);
    // ---- MLP down + residual -> out (fp32) ----
    conv_bf16<<<2048, 256, 0, stream>>>(W2, wbuf, (2048 * 8192) / 8);
    conv_bf16<<<8, 256, 0, stream>>>(b2, b2_c, 2048 / 8);
    gemm256<3><<<(M / 256) * (2048 / 256), 512, 0, stream>>>(
        act_buf, wbuf, b2_c, x2_buf, outp, M, 2048, 8192);
}